// Round 14
// baseline (33.808 us; speedup 1.0000x reference)
//
#include <hip/hip_runtime.h>
#include <hip/hip_fp16.h>

#define U 128
#define NSEG 32
#define NPATH 512
#define ROW (NSEG * U)     // 4096 elements per batch row
#define NW 8               // waves per tp block (512 threads)
#define NMETA 640          // padded meta capacity (max 512 + 32*3 = 608)
#define RPB 2              // rows per block
#define NBLK 1024          // 2048 / RPB -> exactly 4 blocks/CU, one round

// Path metadata, grouped (order-preserving) by pout, each segment's list
// zero-padded to a multiple of 4. pp = p0 | (p1 << 16); c2 = half2{c, c} bits.
struct Meta { unsigned pp; unsigned c2; };
struct WS {
    Meta meta[NMETA];
    int  segstart[NSEG + 1]; // PADDED CSR boundaries (all multiples of 4)
    int  wsplit[NW + 1];     // segment-boundary split per wave
};

template <typename T, typename F> __device__ inline T bcast(F v) {
    union { F f; T t; } u; u.f = v; return u.t;
}

// One block, 512 threads: thread k owns path k. Deterministic parallel
// counting-sort by pout; per-segment lists zero-padded to x4.
__global__ __launch_bounds__(512) void build_csr(const float* __restrict__ coeffs,
                                                 const int* __restrict__ p0,
                                                 const int* __restrict__ p1,
                                                 const int* __restrict__ pout,
                                                 WS* __restrict__ ws) {
    __shared__ int wcnt[NPATH / 64][NSEG];
    __shared__ int wpre[NPATH / 64][NSEG];
    __shared__ int sseg[NSEG + 1];
    __shared__ int stot[NSEG];

    const int k    = threadIdx.x;
    const int lane = k & 63;
    const int wave = k >> 6;

    const int   po = pout[k];
    const int   a0 = p0[k];
    const int   a1 = p1[k];
    const float c  = coeffs[k];

    // zero ALL meta slots (pads must be {pp=0, c2=0})
    for (int i = k; i < NMETA; i += 512) { Meta z; z.pp = 0u; z.c2 = 0u; ws->meta[i] = z; }

    // rank within wave + per-wave counts, via 32 ballots
    const unsigned long long lt = (1ull << lane) - 1ull;
    int rank = 0;
    #pragma unroll
    for (int s = 0; s < NSEG; ++s) {
        unsigned long long m = __ballot(po == s);
        if (po == s)  rank = (int)__popcll(m & lt);
        if (lane == s) wcnt[wave][s] = (int)__popcll(m);
    }
    __syncthreads();

    // per-segment: prefix over waves + totals (threads 0..31)
    if (k < NSEG) {
        int tot = 0;
        #pragma unroll
        for (int w = 0; w < NPATH / 64; ++w) { wpre[w][k] = tot; tot += wcnt[w][k]; }
        stot[k] = tot;
    }
    __syncthreads();

    // exclusive scan of PADDED totals over segments (wave 0)
    if (k < 64) {
        int v = (k < NSEG) ? ((stot[k] + 3) & ~3) : 0;   // pad to x4
        int inc = v;
        #pragma unroll
        for (int d = 1; d < 64; d <<= 1) {
            int t = __shfl_up(inc, d, 64);
            if (k >= d) inc += t;
        }
        int excl = inc - v;
        if (k < NSEG) sseg[k] = excl;
        if (k == NSEG - 1) sseg[NSEG] = excl + v;
    }
    __syncthreads();

    // scatter (deterministic position within padded segment list)
    {
        const __half   h  = __float2half_rn(c);
        const __half2  h2 = __halves2half2(h, h);
        Meta m;
        m.pp = (unsigned)a0 | ((unsigned)a1 << 16);
        m.c2 = bcast<unsigned>(h2);
        ws->meta[sseg[po] + wpre[wave][po] + rank] = m;
    }
    if (k <= NSEG) ws->segstart[k] = sseg[k];

    // balanced NW-way split boundaries on padded counts (wave 0)
    if (k < 64) {
        const int tot = sseg[NSEG];
        #pragma unroll
        for (int w = 1; w < NW; ++w) {
            const int target = (tot * w) / NW;
            int key;
            if (k <= NSEG) {
                int d = sseg[k] - target; if (d < 0) d = -d;
                key = (d << 6) | k;
            } else key = 0x7fffffff;
            #pragma unroll
            for (int m = 32; m >= 1; m >>= 1) {
                int o = __shfl_xor(key, m, 64);
                key = (o < key) ? o : key;
            }
            if (k == 0) ws->wsplit[w] = key & 63;
        }
        if (k == 0) { ws->wsplit[0] = 0; ws->wsplit[NW] = NSEG; }
    }
}

// Barrier that does NOT drain vmcnt: waits only for LDS ops, so prefetched
// global loads (held in regs) stay in flight across it.
__device__ inline void barrier_nodrain() {
    asm volatile("s_waitcnt lgkmcnt(0)\n\ts_barrier" ::: "memory");
}

// One block (512 threads, 8 waves) per TWO batch rows. Row0 staged to LDS
// immediately; row1 held in REGISTERS across row0's compute (its HBM latency
// hides under compute) and written to a separate LDS region after — the
// no-drain barrier keeps row1's loads in flight. Quarter scheme per row:
// lane = 16*g + t; group g takes path j+g; lane reads 8 f16 (ds_read_b128)
// at seg*256B + t*16B (conflict-free). Padded-x4 CSR -> no tails.
__global__ __launch_bounds__(512) void tp_kernel(const float* __restrict__ x0,
                                                 const float* __restrict__ x1,
                                                 const WS* __restrict__ ws,
                                                 float* __restrict__ out) {
    __shared__ __align__(16) __half xh[4 * ROW];   // 32 KiB (row0 ops, row1 ops)
    __shared__ Meta smeta[NMETA];
    __shared__ int  sseg[NSEG + 1];
    __shared__ int  ssplit[NW + 1];

    const int tid = threadIdx.x;
    const int b0  = blockIdx.x * RPB;

    // ---- issue loads in order: meta/csr, row0, row1 (in-order returns) ----
    float4 mv{0.f, 0.f, 0.f, 0.f};
    int sv = 0, wv = 0;
    if (tid < NMETA / 2) mv = reinterpret_cast<const float4*>(ws->meta)[tid];
    if (tid < NSEG + 1)  sv = ws->segstart[tid];
    if (tid < NW + 1)    wv = ws->wsplit[tid];

    const float4* g00 = reinterpret_cast<const float4*>(x0 + (size_t)b0 * ROW);
    const float4* g01 = reinterpret_cast<const float4*>(x1 + (size_t)b0 * ROW);
    const float4* g10 = reinterpret_cast<const float4*>(x0 + (size_t)(b0 + 1) * ROW);
    const float4* g11 = reinterpret_cast<const float4*>(x1 + (size_t)(b0 + 1) * ROW);
    const float4 A0 = g00[tid], A1 = g00[tid + 512];
    const float4 A2 = g01[tid], A3 = g01[tid + 512];
    const float4 B0 = g10[tid], B1 = g10[tid + 512];
    const float4 B2 = g11[tid], B3 = g11[tid + 512];

    // ---- write meta + row0 to LDS (waits only their own loads) ----
    if (tid < NMETA / 2) reinterpret_cast<float4*>(smeta)[tid] = mv;
    if (tid < NSEG + 1)  sseg[tid] = sv;
    if (tid < NW + 1)    ssplit[tid] = wv;

    auto cvtwr = [&](int base, int e, const float4& v) {
        uint2 h;
        h.x = bcast<unsigned>(__float22half2_rn(make_float2(v.x, v.y)));
        h.y = bcast<unsigned>(__float22half2_rn(make_float2(v.z, v.w)));
        *reinterpret_cast<uint2*>(&xh[base + e * 4]) = h;
    };
    cvtwr(0, tid, A0);       cvtwr(0, tid + 512, A1);
    cvtwr(ROW, tid, A2);     cvtwr(ROW, tid + 512, A3);

    barrier_nodrain();   // row1 loads (B*) stay in flight

    const int wave = tid >> 6;
    const int lane = tid & 63;
    const int g    = lane >> 4;    // path group 0..3
    const int t    = lane & 15;    // 8-element slot within a segment

    const int sBeg = __builtin_amdgcn_readfirstlane(ssplit[wave]);
    const int sEnd = __builtin_amdgcn_readfirstlane(ssplit[wave + 1]);
    const int tH   = t * 8;        // half-index offset within a segment

    // compute one row from LDS base (0 or 2*ROW) into outrow
    auto row_compute = [&](int base, float* outrow) {
        const __half* xb = &xh[base];
        for (int s = sBeg; s < sEnd; ++s) {
            const int jb = __builtin_amdgcn_readfirstlane(sseg[s]);
            const int je = __builtin_amdgcn_readfirstlane(sseg[s + 1]);
            __half2 aA0, aA1, aA2, aA3, aB0, aB1, aB2, aB3;
            aA0 = aA1 = aA2 = aA3 = aB0 = aB1 = aB2 = aB3 = bcast<__half2>(0u);
            int j = jb;
            for (; j + 7 < je; j += 8) {   // 2 quads (8 paths) in flight
                const Meta mA = smeta[j + g];
                const Meta mB = smeta[j + 4 + g];
                const uint4 uA = *reinterpret_cast<const uint4*>(
                    &xb[(int)(mA.pp & 0xffffu) * U + tH]);
                const uint4 wA = *reinterpret_cast<const uint4*>(
                    &xb[ROW + (int)(mA.pp >> 16) * U + tH]);
                const uint4 uB = *reinterpret_cast<const uint4*>(
                    &xb[(int)(mB.pp & 0xffffu) * U + tH]);
                const uint4 wB = *reinterpret_cast<const uint4*>(
                    &xb[ROW + (int)(mB.pp >> 16) * U + tH]);
                const __half2 cA = bcast<__half2>(mA.c2);
                const __half2 cB = bcast<__half2>(mB.c2);
                aA0 = __hfma2(__hmul2(bcast<__half2>(uA.x), bcast<__half2>(wA.x)), cA, aA0);
                aA1 = __hfma2(__hmul2(bcast<__half2>(uA.y), bcast<__half2>(wA.y)), cA, aA1);
                aA2 = __hfma2(__hmul2(bcast<__half2>(uA.z), bcast<__half2>(wA.z)), cA, aA2);
                aA3 = __hfma2(__hmul2(bcast<__half2>(uA.w), bcast<__half2>(wA.w)), cA, aA3);
                aB0 = __hfma2(__hmul2(bcast<__half2>(uB.x), bcast<__half2>(wB.x)), cB, aB0);
                aB1 = __hfma2(__hmul2(bcast<__half2>(uB.y), bcast<__half2>(wB.y)), cB, aB1);
                aB2 = __hfma2(__hmul2(bcast<__half2>(uB.z), bcast<__half2>(wB.z)), cB, aB2);
                aB3 = __hfma2(__hmul2(bcast<__half2>(uB.w), bcast<__half2>(wB.w)), cB, aB3);
            }
            if (j < je) {                  // one remaining quad (padded x4)
                const Meta m = smeta[j + g];
                const uint4 u = *reinterpret_cast<const uint4*>(
                    &xb[(int)(m.pp & 0xffffu) * U + tH]);
                const uint4 w = *reinterpret_cast<const uint4*>(
                    &xb[ROW + (int)(m.pp >> 16) * U + tH]);
                const __half2 c = bcast<__half2>(m.c2);
                aA0 = __hfma2(__hmul2(bcast<__half2>(u.x), bcast<__half2>(w.x)), c, aA0);
                aA1 = __hfma2(__hmul2(bcast<__half2>(u.y), bcast<__half2>(w.y)), c, aA1);
                aA2 = __hfma2(__hmul2(bcast<__half2>(u.z), bcast<__half2>(w.z)), c, aA2);
                aA3 = __hfma2(__hmul2(bcast<__half2>(u.w), bcast<__half2>(w.w)), c, aA3);
            }
            __half2 v0 = __hadd2(aA0, aB0);
            __half2 v1 = __hadd2(aA1, aB1);
            __half2 v2 = __hadd2(aA2, aB2);
            __half2 v3 = __hadd2(aA3, aB3);
            #define RED(v)                                                    \
                v = __hadd2(v, bcast<__half2>((unsigned)__shfl_xor(           \
                                (int)bcast<unsigned>(v), 16, 64)));           \
                v = __hadd2(v, bcast<__half2>((unsigned)__shfl_xor(           \
                                (int)bcast<unsigned>(v), 32, 64)));
            RED(v0) RED(v1) RED(v2) RED(v3)
            #undef RED
            const float2 lo = __half22float2((g & 1) ? v2 : v0);
            const float2 hi = __half22float2((g & 1) ? v3 : v1);
            if (g < 2) {
                float4 o;
                o.x = lo.x; o.y = lo.y; o.z = hi.x; o.w = hi.y;
                reinterpret_cast<float4*>(outrow + s * U)[t * 2 + g] = o;
            }
        }
    };

    row_compute(0, out + (size_t)b0 * ROW);

    // ---- stage row1 (first use of B -> compiler waits its vmcnt here) ----
    cvtwr(2 * ROW, tid, B0);   cvtwr(2 * ROW, tid + 512, B1);
    cvtwr(3 * ROW, tid, B2);   cvtwr(3 * ROW, tid + 512, B3);
    barrier_nodrain();   // row0 output stores stay in flight

    row_compute(2 * ROW, out + (size_t)(b0 + 1) * ROW);
}

extern "C" void kernel_launch(void* const* d_in, const int* in_sizes, int n_in,
                              void* d_out, int out_size, void* d_ws, size_t ws_size,
                              hipStream_t stream) {
    const float* x0     = (const float*)d_in[0];
    const float* x1     = (const float*)d_in[1];
    const float* coeffs = (const float*)d_in[2];
    const int*   p0     = (const int*)d_in[3];
    const int*   p1     = (const int*)d_in[4];
    const int*   pout   = (const int*)d_in[5];
    float* out = (float*)d_out;
    WS* ws = (WS*)d_ws;

    build_csr<<<1, 512, 0, stream>>>(coeffs, p0, p1, pout, ws);
    tp_kernel<<<NBLK, 512, 0, stream>>>(x0, x1, ws, out);
}